// Round 19
// baseline (472.310 us; speedup 1.0000x reference)
//
#include <hip/hip_runtime.h>
#include <math.h>

#define CH 1024
#define LOG2E 1.4426950408889634f

typedef __attribute__((ext_vector_type(8))) short bf16x8;
typedef __attribute__((ext_vector_type(4))) float f32x4;
typedef __attribute__((ext_vector_type(4))) unsigned u32x4;

__device__ __forceinline__ float rcp_(float x){ return __builtin_amdgcn_rcpf(x); }
__device__ __forceinline__ float exp2_(float x){ return exp2f(x); }   // native v_exp_f32 (2^x)
__device__ __forceinline__ unsigned short f2bf(float f){
  union{float f;unsigned u;}v; v.f=f;
  unsigned r = v.u + 0x7fffu + ((v.u>>16)&1u);
  return (unsigned short)(r>>16);
}
__device__ __forceinline__ float bf2f(unsigned short u){
  union{unsigned u; float f;} v; v.u = ((unsigned)u) << 16; return v.f;
}

// ---------- CSR build ----------
__global__ __launch_bounds__(256) void count_rank(const int* __restrict__ ei, int* __restrict__ cnt,
                                                  int* __restrict__ rank, int E){
  int e = blockIdx.x*256 + threadIdx.x;
  if (e < E) rank[e] = atomicAdd(&cnt[ei[E + e]], 1);
}

__global__ __launch_bounds__(256) void scan_partial(const int* __restrict__ cnt, int* __restrict__ bsum, int N){
  __shared__ int s[256];
  int b = blockIdx.x, t = threadIdx.x;
  int base = b*CH;
  int sum = 0;
  for (int i = t; i < CH; i += 256){ int idx = base + i; sum += (idx < N) ? cnt[idx] : 0; }
  s[t] = sum; __syncthreads();
  for (int off = 128; off > 0; off >>= 1){ if (t < off) s[t] += s[t+off]; __syncthreads(); }
  if (t == 0) bsum[b] = s[0];
}

__global__ void scan_bsum(int* __restrict__ bsum, int B){
  if (threadIdx.x == 0 && blockIdx.x == 0){
    int acc = 0;
    for (int i = 0; i < B; i++){ int v = bsum[i]; bsum[i] = acc; acc += v; }
  }
}

__global__ __launch_bounds__(256) void scan_final(const int* __restrict__ cnt, const int* __restrict__ bsum,
                                                  int* __restrict__ off, float* __restrict__ degf, int N, int E){
  __shared__ int s[256];
  __shared__ int sx[256];
  int b = blockIdx.x, t = threadIdx.x;
  int i0 = b*CH + t*4;
  int v0 = (i0   < N) ? cnt[i0]   : 0;
  int v1 = (i0+1 < N) ? cnt[i0+1] : 0;
  int v2 = (i0+2 < N) ? cnt[i0+2] : 0;
  int v3 = (i0+3 < N) ? cnt[i0+3] : 0;
  s[t] = v0+v1+v2+v3; __syncthreads();
  if (t == 0){ int acc = bsum[b]; for (int i = 0; i < 256; i++){ sx[i] = acc; acc += s[i]; } }
  __syncthreads();
  int acc = sx[t];
  if (i0   < N){ off[i0]   = acc; degf[i0]   = (float)v0; } acc += v0;
  if (i0+1 < N){ off[i0+1] = acc; degf[i0+1] = (float)v1; } acc += v1;
  if (i0+2 < N){ off[i0+2] = acc; degf[i0+2] = (float)v2; } acc += v2;
  if (i0+3 < N){ off[i0+3] = acc; degf[i0+3] = (float)v3; }
  if (b == 0 && t == 0) off[N] = E;
}

// pre-convert x rows to bf16 hi/lo, 64B-aligned: [hi0..7|16B][lo0..7|16B][hi8,lo8|4B][pad]
__global__ __launch_bounds__(256) void xpack_kernel(const float* __restrict__ x, unsigned short* __restrict__ xp, int N){
  int n = blockIdx.x*256 + threadIdx.x;
  if (n >= N) return;
  const float* xr = x + (size_t)n*9;
  union { unsigned short us[32]; u32x4 q[4]; } row;
  #pragma unroll
  for (int i = 0; i < 9; i++){
    unsigned short hi = f2bf(xr[i]);
    unsigned short lo = f2bf(xr[i] - bf2f(hi));
    if (i < 8){ row.us[i] = hi; row.us[8+i] = lo; }
    else { row.us[16] = hi; row.us[17] = lo; }
  }
  #pragma unroll
  for (int i = 18; i < 32; i++) row.us[i] = 0;
  u32x4* dstp = (u32x4*)(xp + (size_t)n*32);
  dstp[0] = row.q[0]; dstp[1] = row.q[1]; dstp[2] = row.q[2]; dstp[3] = row.q[3];
}

// atomic-free fill: one 64B fully-dirty line per edge (non-temporal stores).
// x arrives pre-packed (one-line gather, no conversion); only ea is converted here.
__global__ __launch_bounds__(256) void fill64(const int* __restrict__ ei, const unsigned short* __restrict__ xp,
                                              const float* __restrict__ ea, const int* __restrict__ off,
                                              const int* __restrict__ rank, float* __restrict__ csr2, int E){
  int e = blockIdx.x*256 + threadIdx.x;
  if (e >= E) return;
  int dst = ei[E + e];
  int src = ei[e];
  int p = off[dst] + rank[e];
  const u32x4* xr4 = (const u32x4*)(xp + (size_t)src*32);
  u32x4 q0 = xr4[0];                       // hi0..7
  u32x4 q1 = xr4[1];                       // lo0..7
  unsigned hl8 = *(const unsigned*)(xp + (size_t)src*32 + 16);  // hi8|lo8
  const float* er = ea + (size_t)e*3;
  float e0 = er[0], e1 = er[1], e2 = er[2];
  unsigned short eh0 = f2bf(e0), eh1 = f2bf(e1), eh2 = f2bf(e2);
  unsigned short el0 = f2bf(e0 - bf2f(eh0));
  unsigned short el1 = f2bf(e1 - bf2f(eh1));
  unsigned short el2 = f2bf(e2 - bf2f(eh2));
  // q2 = [hi8, eh0, eh1, eh2, lo8, el0, el1, el2]
  u32x4 q2;
  q2.x = (hl8 & 0xFFFFu) | ((unsigned)eh0 << 16);
  q2.y = (unsigned)eh1 | ((unsigned)eh2 << 16);
  q2.z = (hl8 >> 16)    | ((unsigned)el0 << 16);
  q2.w = (unsigned)el1 | ((unsigned)el2 << 16);
  u32x4 q3 = {0u, 0u, 0u, 0u};
  u32x4* row = (u32x4*)(csr2 + (size_t)p*16);
  __builtin_nontemporal_store(q0, row + 0);
  __builtin_nontemporal_store(q1, row + 1);
  __builtin_nontemporal_store(q2, row + 2);
  __builtin_nontemporal_store(q3, row + 3);
}

// pack a [192][64] gate matrix into bf16 B-fragments, with per-gate scaling
__global__ __launch_bounds__(256) void pack_frag(const float* __restrict__ W, unsigned short* __restrict__ P,
                                                 float sRZ, float sN){
  int o = blockIdx.x*256 + threadIdx.x;
  if (o >= 12288) return;
  int j = o & 7, l = (o>>3)&63, kh = (o>>9)&1, c = o>>10;
  float sc = (c < 8) ? sRZ : sN;
  P[o] = f2bf(sc * W[(c*16 + (l&15))*64 + kh*32 + 8*(l>>4) + j]);
}

// W1 [64][12] -> two B-fragment sets over K=32 (hi/lo split)
__global__ __launch_bounds__(256) void pack_w1(const float* __restrict__ W1,
    unsigned short* __restrict__ B1, unsigned short* __restrict__ B2){
  int o = blockIdx.x*256 + threadIdx.x;
  if (o >= 2048) return;
  int j = o & 7, l = (o>>3) & 63, c = o >> 9;
  int n = c*16 + (l & 15);
  int kk = 8*(l>>4) + j;
  unsigned short b1v = 0, b2v = 0;
  if (kk < 12){
    float w = W1[n*12 + kk];
    unsigned short hi = f2bf(w);
    b1v = hi;
    b2v = f2bf(w - bf2f(hi));
  } else if (kk >= 16 && kk < 28){
    b1v = f2bf(W1[n*12 + (kk-16)]);
  }
  B1[o] = b1v; B2[o] = b2v;
}

// M = (Wih @ W2) scaled per gate; dv = (Wih @ b2) scaled per gate.
__global__ __launch_bounds__(256) void make_M(const float* __restrict__ Wih, const float* __restrict__ W2,
    const float* __restrict__ b2, float* __restrict__ M, float* __restrict__ dv){
  int idx = blockIdx.x*256 + threadIdx.x;
  if (idx >= 12288) return;
  int o = idx >> 6, k = idx & 63;
  float sc = (o < 128) ? -LOG2E : 2.0f*LOG2E;
  float acc = 0.0f;
  for (int j = 0; j < 64; j++) acc += Wih[o*64+j]*W2[j*64+k];
  M[idx] = sc * acc;
  if (k == 0){
    float a2 = 0.0f;
    for (int j = 0; j < 64; j++) a2 += Wih[o*64+j]*b2[j];
    dv[o] = sc * a2;
  }
}

// ---------- per-node layer-1 + segment-sum on MFMA (pre-converted rows) ----------
__global__ __launch_bounds__(256, 2) void node_msg_kernel(
    const float* __restrict__ csr2, const int* __restrict__ off,
    const unsigned short* __restrict__ W1B1v, const unsigned short* __restrict__ W1B2v,
    const float* __restrict__ b1, float* __restrict__ hsum, int N)
{
  int t = threadIdx.x, lane = t & 63;
  int s_ = lane & 15, g_ = lane >> 4;
  const bf16x8* B1 = (const bf16x8*)W1B1v;
  const bf16x8* B2 = (const bf16x8*)W1B2v;
  bf16x8 w1b1[4], w1b2[4];
  #pragma unroll
  for (int c = 0; c < 4; c++){ w1b1[c] = B1[c*64+lane]; w1b2[c] = B2[c*64+lane]; }
  float b1f[4], rb1[4];
  #pragma unroll
  for (int c = 0; c < 4; c++){ b1f[c] = b1[c*16+s_]; rb1[c] = fmaxf(b1f[c], 0.f); }
  bool hi_ = (g_ < 2);
  int rofs_us = (g_ == 0) ? 0 : (g_ == 2) ? 8 : (g_ == 1) ? 16 : 20;
  int wid = (blockIdx.x*256 + t) >> 6;
  int nw = gridDim.x*4;
  for (int node = wid; node < N; node += nw){
    int s = off[node], e = off[node+1];
    float accR[4] = {0.f,0.f,0.f,0.f};
    int ntiles = (e - s + 15) >> 4;
    for (int tt = 0; tt < ntiles; tt++){
      int p = s + tt*16 + s_;
      bf16x8 af = {0,0,0,0,0,0,0,0};
      if (p < e){
        const unsigned short* row = (const unsigned short*)(csr2 + (size_t)p*16);
        if ((g_ & 1) == 0){
          af = *(const bf16x8*)(row + rofs_us);
        } else {
          short4 v = *(const short4*)(row + rofs_us);
          af[0]=v.x; af[1]=v.y; af[2]=v.z; af[3]=v.w;
        }
      }
      bf16x8 ah = hi_ ? af : (bf16x8){0,0,0,0,0,0,0,0};
      #pragma unroll
      for (int c = 0; c < 4; c++){
        f32x4 acc; acc[0]=b1f[c]; acc[1]=b1f[c]; acc[2]=b1f[c]; acc[3]=b1f[c];
        acc = __builtin_amdgcn_mfma_f32_16x16x32_bf16(af, w1b1[c], acc, 0,0,0);
        acc = __builtin_amdgcn_mfma_f32_16x16x32_bf16(ah, w1b2[c], acc, 0,0,0);
        accR[c] += fmaxf(acc[0],0.f)+fmaxf(acc[1],0.f)+fmaxf(acc[2],0.f)+fmaxf(acc[3],0.f);
      }
    }
    float npad = (float)(ntiles*16 - (e - s));
    #pragma unroll
    for (int c = 0; c < 4; c++){
      float v = accR[c] - npad*rb1[c];
      v += __shfl_xor(v, 16, 64);
      v += __shfl_xor(v, 32, 64);
      accR[c] = v;
    }
    float outv = (g_==0) ? accR[0] : ((g_==1) ? accR[1] : ((g_==2) ? accR[2] : accR[3]));
    hsum[(size_t)node*64 + lane] = outv;
  }
}

// ---------- fused (M@hsum + deg*dv + bih) + 6-step GRU on matrix cores ----------
__global__ __launch_bounds__(256, 2) void gru_mfma(
    float* hsumh,
    const unsigned short* __restrict__ MF, const unsigned short* __restrict__ WhhF,
    const float* __restrict__ bih, const float* __restrict__ bhh,
    const float* __restrict__ dv, const float* __restrict__ degf, int N)
{
  __shared__ __align__(16) unsigned short swhh[12288];   // 24 KB
  __shared__ unsigned short hbuf[4][1024];               // 8 KB
  __shared__ float sbi[192], sbh[192], sdv[192];         // 2.25 KB
  int t = threadIdx.x, lane = t & 63, w = t >> 6;
  int s_ = lane & 15, g_ = lane >> 4;
  unsigned short* hb = hbuf[w];

  {
    const u32x4* src = (const u32x4*)WhhF;
    u32x4* dst = (u32x4*)swhh;
    #pragma unroll
    for (int i = 0; i < 6; i++) dst[t + 256*i] = src[t + 256*i];
  }
  if (t < 192){ sbi[t] = bih[t]; sbh[t] = bhh[t]; sdv[t] = dv[t]; }
  __syncthreads();

  const bf16x8* WHH = (const bf16x8*)swhh;
  const bf16x8* MFV = (const bf16x8*)MF;

  float bhn[4];
  #pragma unroll
  for (int c = 0; c < 4; c++) bhn[c] = 2.0f*LOG2E * sbh[128 + c*16 + s_];

  int NT = (N + 15) >> 4;
  int wid = blockIdx.x*4 + w;
  int nw = gridDim.x*4;
  for (int tile = wid; tile < NT; tile += nw){
    // ---- A-fragments of hsum tile (16 nodes x 64 feats) ----
    int nodeA = tile*16 + s_; if (nodeA > N-1) nodeA = N-1;
    const float* ab = hsumh + (size_t)nodeA*64 + g_*8;
    float4 v0 = *(const float4*)(ab);
    float4 v1 = *(const float4*)(ab+4);
    float4 v2 = *(const float4*)(ab+32);
    float4 v3 = *(const float4*)(ab+36);
    bf16x8 a0, a1;
    a0[0]=(short)f2bf(v0.x); a0[1]=(short)f2bf(v0.y); a0[2]=(short)f2bf(v0.z); a0[3]=(short)f2bf(v0.w);
    a0[4]=(short)f2bf(v1.x); a0[5]=(short)f2bf(v1.y); a0[6]=(short)f2bf(v1.z); a0[7]=(short)f2bf(v1.w);
    a1[0]=(short)f2bf(v2.x); a1[1]=(short)f2bf(v2.y); a1[2]=(short)f2bf(v2.z); a1[3]=(short)f2bf(v2.w);
    a1[4]=(short)f2bf(v3.x); a1[5]=(short)f2bf(v3.y); a1[6]=(short)f2bf(v3.z); a1[7]=(short)f2bf(v3.w);

    // ---- gi (pre-scaled): gb = sc*(bih [+bhh]) + deg*dv' + M'@hsum, bf16-packed ----
    float4 dr = *(const float4*)(degf + tile*16 + 4*g_);
    float drr[4] = {dr.x, dr.y, dr.z, dr.w};
    bf16x8 gb[6];
    #pragma unroll
    for (int c = 0; c < 12; c++){
      float sc = (c < 8) ? -LOG2E : 2.0f*LOG2E;
      float bic = sc * (sbi[c*16 + s_] + ((c < 8) ? sbh[c*16 + s_] : 0.0f));
      float dvc = sdv[c*16 + s_];   // pre-scaled in make_M
      f32x4 acc;
      #pragma unroll
      for (int r = 0; r < 4; r++) acc[r] = bic + drr[r]*dvc;
      acc = __builtin_amdgcn_mfma_f32_16x16x32_bf16(a0, MFV[(c*2+0)*64 + lane], acc, 0, 0, 0);
      acc = __builtin_amdgcn_mfma_f32_16x16x32_bf16(a1, MFV[(c*2+1)*64 + lane], acc, 0, 0, 0);
      #pragma unroll
      for (int r = 0; r < 4; r++) gb[c>>1][(c&1)*4 + r] = (short)f2bf(acc[r]);
    }

    // ---- 6 GRU steps ----
    f32x4 hD[4];
    #pragma unroll
    for (int c = 0; c < 4; c++){ hD[c][0]=0.f; hD[c][1]=0.f; hD[c][2]=0.f; hD[c][3]=0.f; }
    bf16x8 h0 = {0,0,0,0,0,0,0,0};
    bf16x8 h1 = {0,0,0,0,0,0,0,0};
    for (int st = 0; st < 6; st++){
      // Opaque zero: defeats LICM hoisting of the 24 WHH ds_reads (R13 spill source).
      int zofs = 0;
      asm volatile("" : "+v"(zofs));
      #pragma unroll
      for (int c = 0; c < 4; c++){
        f32x4 aR, aZ, aN, giN;
        #pragma unroll
        for (int r = 0; r < 4; r++){
          aR[r]  = bf2f((unsigned short)gb[c>>1][(c&1)*4 + r]);
          aZ[r]  = bf2f((unsigned short)gb[(4+c)>>1][((4+c)&1)*4 + r]);
          giN[r] = bf2f((unsigned short)gb[(8+c)>>1][((8+c)&1)*4 + r]);
        }
        aN[0]=bhn[c]; aN[1]=bhn[c]; aN[2]=bhn[c]; aN[3]=bhn[c];
        aR = __builtin_amdgcn_mfma_f32_16x16x32_bf16(h0, WHH[(c*2)*64 + lane + zofs],       aR, 0,0,0);
        aR = __builtin_amdgcn_mfma_f32_16x16x32_bf16(h1, WHH[(c*2+1)*64 + lane + zofs],     aR, 0,0,0);
        aZ = __builtin_amdgcn_mfma_f32_16x16x32_bf16(h0, WHH[((4+c)*2)*64 + lane + zofs],   aZ, 0,0,0);
        aZ = __builtin_amdgcn_mfma_f32_16x16x32_bf16(h1, WHH[((4+c)*2+1)*64 + lane + zofs], aZ, 0,0,0);
        aN = __builtin_amdgcn_mfma_f32_16x16x32_bf16(h0, WHH[((8+c)*2)*64 + lane + zofs],   aN, 0,0,0);
        aN = __builtin_amdgcn_mfma_f32_16x16x32_bf16(h1, WHH[((8+c)*2+1)*64 + lane + zofs], aN, 0,0,0);
        #pragma unroll
        for (int r = 0; r < 4; r++){
          float rr = rcp_(1.0f + exp2_(aR[r]));
          float zz = rcp_(1.0f + exp2_(aZ[r]));
          float nn = 1.0f - 2.0f*rcp_(1.0f + exp2_(giN[r] + rr*aN[r]));
          hD[c][r] = nn + zz*(hD[c][r] - nn);
        }
      }
      if (st < 5){
        #pragma unroll
        for (int c = 0; c < 4; c++){
          #pragma unroll
          for (int r = 0; r < 4; r++){
            int nl = 4*g_ + r;
            int idx = (nl*64 + 16*c + s_) ^ ((nl & 7) << 3);
            hb[idx] = f2bf(hD[c][r]);
          }
        }
        int r0 = (s_*64 +      8*g_) ^ ((s_ & 7) << 3);
        int r1 = (s_*64 + 32 + 8*g_) ^ ((s_ & 7) << 3);
        h0 = *(const bf16x8*)(hb + r0);
        h1 = *(const bf16x8*)(hb + r1);
      }
    }
    // ---- store h ----
    #pragma unroll
    for (int c = 0; c < 4; c++){
      #pragma unroll
      for (int r = 0; r < 4; r++){
        int node = tile*16 + 4*g_ + r;
        if (node < N) hsumh[(size_t)node*64 + 16*c + s_] = hD[c][r];
      }
    }
  }
}

// ---------- graph ranges via binary search on sorted batch ----------
__global__ __launch_bounds__(256) void gstart_kernel(const int* __restrict__ batch, int* __restrict__ gstart, int N, int G){
  int g = blockIdx.x*256 + threadIdx.x;
  if (g > G) return;
  int lo = 0, hi = N;
  while (lo < hi){ int mid = (lo + hi) >> 1; if (batch[mid] < g) lo = mid + 1; else hi = mid; }
  gstart[g] = lo;
}

// wave per graph: mean over the graph's node range
__global__ __launch_bounds__(64) void pool_kernel(const float* __restrict__ hout, const int* __restrict__ gstart,
                                                  float* __restrict__ pooled, int G){
  int g = blockIdx.x; int lane = threadIdx.x;
  int s = gstart[g], e = gstart[g+1];
  float acc = 0.0f;
  for (int n = s; n < e; n++) acc += hout[(size_t)n*64 + lane];
  float c = fmaxf((float)(e - s), 1.0f);
  pooled[g*64 + lane] = acc / c;
}

// thread per graph: out = W2 relu(W1 pooled + b1) + b2
__global__ __launch_bounds__(256) void readout_kernel(
  const float* __restrict__ pooled,
  const float* __restrict__ W1, const float* __restrict__ b1,
  const float* __restrict__ W2, const float* __restrict__ b2,
  float* __restrict__ out, int G)
{
  __shared__ __align__(16) float sW1[64*64];
  __shared__ float sb1[64], sW2v[64];
  for (int i = threadIdx.x; i < 64*64; i += 256) sW1[i] = W1[i];
  if (threadIdx.x < 64){ sb1[threadIdx.x] = b1[threadIdx.x]; sW2v[threadIdx.x] = W2[threadIdx.x]; }
  __syncthreads();
  int g = blockIdx.x*256 + threadIdx.x;
  if (g >= G) return;
  float p[64];
  const float4* pp = (const float4*)(pooled + g*64);
  #pragma unroll
  for (int k4 = 0; k4 < 16; k4++){
    float4 v = pp[k4];
    p[4*k4] = v.x; p[4*k4+1] = v.y; p[4*k4+2] = v.z; p[4*k4+3] = v.w;
  }
  float acc = b2[0];
  for (int j = 0; j < 64; j++){
    const float4* wv4 = (const float4*)(sW1 + j*64);
    float tacc = sb1[j];
    #pragma unroll
    for (int k4 = 0; k4 < 16; k4++){
      float4 wv = wv4[k4];
      tacc += wv.x*p[4*k4] + wv.y*p[4*k4+1] + wv.z*p[4*k4+2] + wv.w*p[4*k4+3];
    }
    acc += sW2v[j]*fmaxf(tacc, 0.0f);
  }
  out[g] = acc;
}

extern "C" void kernel_launch(void* const* d_in, const int* in_sizes, int n_in,
                              void* d_out, int out_size, void* d_ws, size_t ws_size,
                              hipStream_t stream)
{
  const float* x    = (const float*)d_in[0];
  const int*   ei   = (const int*)  d_in[1];
  const float* ea   = (const float*)d_in[2];
  const int*   batch= (const int*)  d_in[3];
  const float* mW1  = (const float*)d_in[4];
  const float* mb1  = (const float*)d_in[5];
  const float* mW2  = (const float*)d_in[6];
  const float* mb2  = (const float*)d_in[7];
  const float* Wih  = (const float*)d_in[8];
  const float* Whh  = (const float*)d_in[9];
  const float* bih  = (const float*)d_in[10];
  const float* bhh  = (const float*)d_in[11];
  const float* rW1  = (const float*)d_in[12];
  const float* rb1  = (const float*)d_in[13];
  const float* rW2  = (const float*)d_in[14];
  const float* rb2  = (const float*)d_in[15];
  float* out = (float*)d_out;

  int N = in_sizes[0] / 9;
  int E = in_sizes[1] / 2;
  int G = out_size;

  float* fws    = (float*)d_ws;
  float* hsum   = fws;                          // 64N floats (in: hsum, out: h)
  int*   rank   = (int*)hsum;                   // E ints, aliases hsum
  float* csr2   = hsum + (size_t)64*N;          // 16E floats (64B rows, bf16 hi/lo layout)
  float* degf   = csr2 + (size_t)16*E;          // N+16
  float* M      = degf + (size_t)(N+16);        // 12288
  float* dv     = M + 12288;                    // 192
  float* pooled = dv + 192;                     // 64G
  unsigned short* MF   = (unsigned short*)(pooled + (size_t)64*G);  // 12288
  unsigned short* WhhF = MF + 12288;                                 // 12288
  unsigned short* W1B1 = WhhF + 12288;                               // 2048
  unsigned short* W1B2 = W1B1 + 2048;                                // 2048
  unsigned short* xp   = W1B2 + 2048;                                // 32N ushorts (64B rows)
  int*   iws    = (int*)(xp + (size_t)32*N);
  int*   cnt    = iws;                          // N
  int*   off    = cnt + N;                      // N+1
  int*   bsum   = off + N + 1;                  // up to 1024
  int*   gstart = bsum + 1024;                  // G+1

  int B1 = (N + CH - 1) / CH;

  hipMemsetAsync(cnt, 0, (size_t)N*sizeof(int), stream);
  hipMemsetAsync(degf + N, 0, 16*sizeof(float), stream);

  count_rank<<<(E+255)/256, 256, 0, stream>>>(ei, cnt, rank, E);
  scan_partial<<<B1, 256, 0, stream>>>(cnt, bsum, N);
  scan_bsum<<<1, 64, 0, stream>>>(bsum, B1);
  scan_final<<<B1, 256, 0, stream>>>(cnt, bsum, off, degf, N, E);
  xpack_kernel<<<(N+255)/256, 256, 0, stream>>>(x, xp, N);
  fill64<<<(E+255)/256, 256, 0, stream>>>(ei, xp, ea, off, rank, csr2, E);

  pack_w1<<<8, 256, 0, stream>>>(mW1, W1B1, W1B2);
  make_M<<<48, 256, 0, stream>>>(Wih, mW2, mb2, M, dv);
  pack_frag<<<48, 256, 0, stream>>>(M, MF, 1.0f, 1.0f);
  pack_frag<<<48, 256, 0, stream>>>(Whh, WhhF, -LOG2E, 2.0f*LOG2E);

  node_msg_kernel<<<1024, 256, 0, stream>>>(csr2, off, W1B1, W1B2, mb1, hsum, N);

  gru_mfma<<<1024, 256, 0, stream>>>(hsum, MF, WhhF, bih, bhh, dv, degf, N);

  gstart_kernel<<<(G+256)/256, 256, 0, stream>>>(batch, gstart, N, G);
  pool_kernel<<<G, 64, 0, stream>>>(hsum, gstart, pooled, G);
  readout_kernel<<<(G+255)/256, 256, 0, stream>>>(pooled, rW1, rb1, rW2, rb2, out, G);
}

// Round 20
// 332.921 us; speedup vs baseline: 1.4187x; 1.4187x over previous
//
#include <hip/hip_runtime.h>
#include <math.h>

#define CH 1024
#define LOG2E 1.4426950408889634f

typedef __attribute__((ext_vector_type(8))) short bf16x8;
typedef __attribute__((ext_vector_type(4))) float f32x4;
typedef __attribute__((ext_vector_type(4))) unsigned u32x4;

__device__ __forceinline__ float rcp_(float x){ return __builtin_amdgcn_rcpf(x); }
__device__ __forceinline__ float exp2_(float x){ return exp2f(x); }   // native v_exp_f32 (2^x)
__device__ __forceinline__ unsigned short f2bf(float f){
  union{float f;unsigned u;}v; v.f=f;
  unsigned r = v.u + 0x7fffu + ((v.u>>16)&1u);
  return (unsigned short)(r>>16);
}
__device__ __forceinline__ float bf2f(unsigned short u){
  union{unsigned u; float f;} v; v.u = ((unsigned)u) << 16; return v.f;
}

// ---------- CSR build ----------
__global__ __launch_bounds__(256) void count_rank(const int* __restrict__ ei, int* __restrict__ cnt,
                                                  int* __restrict__ rank, int E){
  int e = blockIdx.x*256 + threadIdx.x;
  if (e < E) rank[e] = atomicAdd(&cnt[ei[E + e]], 1);
}

__global__ __launch_bounds__(256) void scan_partial(const int* __restrict__ cnt, int* __restrict__ bsum, int N){
  __shared__ int s[256];
  int b = blockIdx.x, t = threadIdx.x;
  int base = b*CH;
  int sum = 0;
  for (int i = t; i < CH; i += 256){ int idx = base + i; sum += (idx < N) ? cnt[idx] : 0; }
  s[t] = sum; __syncthreads();
  for (int off = 128; off > 0; off >>= 1){ if (t < off) s[t] += s[t+off]; __syncthreads(); }
  if (t == 0) bsum[b] = s[0];
}

__global__ void scan_bsum(int* __restrict__ bsum, int B){
  if (threadIdx.x == 0 && blockIdx.x == 0){
    int acc = 0;
    for (int i = 0; i < B; i++){ int v = bsum[i]; bsum[i] = acc; acc += v; }
  }
}

__global__ __launch_bounds__(256) void scan_final(const int* __restrict__ cnt, const int* __restrict__ bsum,
                                                  int* __restrict__ off, float* __restrict__ degf, int N, int E){
  __shared__ int s[256];
  __shared__ int sx[256];
  int b = blockIdx.x, t = threadIdx.x;
  int i0 = b*CH + t*4;
  int v0 = (i0   < N) ? cnt[i0]   : 0;
  int v1 = (i0+1 < N) ? cnt[i0+1] : 0;
  int v2 = (i0+2 < N) ? cnt[i0+2] : 0;
  int v3 = (i0+3 < N) ? cnt[i0+3] : 0;
  s[t] = v0+v1+v2+v3; __syncthreads();
  if (t == 0){ int acc = bsum[b]; for (int i = 0; i < 256; i++){ sx[i] = acc; acc += s[i]; } }
  __syncthreads();
  int acc = sx[t];
  if (i0   < N){ off[i0]   = acc; degf[i0]   = (float)v0; } acc += v0;
  if (i0+1 < N){ off[i0+1] = acc; degf[i0+1] = (float)v1; } acc += v1;
  if (i0+2 < N){ off[i0+2] = acc; degf[i0+2] = (float)v2; } acc += v2;
  if (i0+3 < N){ off[i0+3] = acc; degf[i0+3] = (float)v3; }
  if (b == 0 && t == 0) off[N] = E;
}

// pre-convert x rows to bf16 hi/lo, 64B-aligned: [hi0..7|16B][lo0..7|16B][hi8,lo8|4B][pad]
__global__ __launch_bounds__(256) void xpack_kernel(const float* __restrict__ x, unsigned short* __restrict__ xp, int N){
  int n = blockIdx.x*256 + threadIdx.x;
  if (n >= N) return;
  const float* xr = x + (size_t)n*9;
  union { unsigned short us[32]; u32x4 q[4]; } row;
  #pragma unroll
  for (int i = 0; i < 9; i++){
    unsigned short hi = f2bf(xr[i]);
    unsigned short lo = f2bf(xr[i] - bf2f(hi));
    if (i < 8){ row.us[i] = hi; row.us[8+i] = lo; }
    else { row.us[16] = hi; row.us[17] = lo; }
  }
  #pragma unroll
  for (int i = 18; i < 32; i++) row.us[i] = 0;
  u32x4* dstp = (u32x4*)(xp + (size_t)n*32);
  dstp[0] = row.q[0]; dstp[1] = row.q[1]; dstp[2] = row.q[2]; dstp[3] = row.q[3];
}

// atomic-free fill: one 64B fully-dirty line per edge (PLAIN stores — L2 merges
// the four 16B stores into one dirty line; R19's NT stores bypassed L2 and
// caused 4x partial-line write amplification, 104->238 MB).
// x arrives pre-packed (one-line gather, no conversion); only ea is converted here.
__global__ __launch_bounds__(256) void fill64(const int* __restrict__ ei, const unsigned short* __restrict__ xp,
                                              const float* __restrict__ ea, const int* __restrict__ off,
                                              const int* __restrict__ rank, float* __restrict__ csr2, int E){
  int e = blockIdx.x*256 + threadIdx.x;
  if (e >= E) return;
  int dst = ei[E + e];
  int src = ei[e];
  int p = off[dst] + rank[e];
  const u32x4* xr4 = (const u32x4*)(xp + (size_t)src*32);
  u32x4 q0 = xr4[0];                       // hi0..7
  u32x4 q1 = xr4[1];                       // lo0..7
  unsigned hl8 = *(const unsigned*)(xp + (size_t)src*32 + 16);  // hi8|lo8
  const float* er = ea + (size_t)e*3;
  float e0 = er[0], e1 = er[1], e2 = er[2];
  unsigned short eh0 = f2bf(e0), eh1 = f2bf(e1), eh2 = f2bf(e2);
  unsigned short el0 = f2bf(e0 - bf2f(eh0));
  unsigned short el1 = f2bf(e1 - bf2f(eh1));
  unsigned short el2 = f2bf(e2 - bf2f(eh2));
  // q2 = [hi8, eh0, eh1, eh2, lo8, el0, el1, el2]
  u32x4 q2;
  q2.x = (hl8 & 0xFFFFu) | ((unsigned)eh0 << 16);
  q2.y = (unsigned)eh1 | ((unsigned)eh2 << 16);
  q2.z = (hl8 >> 16)    | ((unsigned)el0 << 16);
  q2.w = (unsigned)el1 | ((unsigned)el2 << 16);
  u32x4 q3 = {0u, 0u, 0u, 0u};
  u32x4* row = (u32x4*)(csr2 + (size_t)p*16);
  row[0] = q0; row[1] = q1; row[2] = q2; row[3] = q3;
}

// pack a [192][64] gate matrix into bf16 B-fragments, with per-gate scaling
__global__ __launch_bounds__(256) void pack_frag(const float* __restrict__ W, unsigned short* __restrict__ P,
                                                 float sRZ, float sN){
  int o = blockIdx.x*256 + threadIdx.x;
  if (o >= 12288) return;
  int j = o & 7, l = (o>>3)&63, kh = (o>>9)&1, c = o>>10;
  float sc = (c < 8) ? sRZ : sN;
  P[o] = f2bf(sc * W[(c*16 + (l&15))*64 + kh*32 + 8*(l>>4) + j]);
}

// W1 [64][12] -> two B-fragment sets over K=32 (hi/lo split)
__global__ __launch_bounds__(256) void pack_w1(const float* __restrict__ W1,
    unsigned short* __restrict__ B1, unsigned short* __restrict__ B2){
  int o = blockIdx.x*256 + threadIdx.x;
  if (o >= 2048) return;
  int j = o & 7, l = (o>>3) & 63, c = o >> 9;
  int n = c*16 + (l & 15);
  int kk = 8*(l>>4) + j;
  unsigned short b1v = 0, b2v = 0;
  if (kk < 12){
    float w = W1[n*12 + kk];
    unsigned short hi = f2bf(w);
    b1v = hi;
    b2v = f2bf(w - bf2f(hi));
  } else if (kk >= 16 && kk < 28){
    b1v = f2bf(W1[n*12 + (kk-16)]);
  }
  B1[o] = b1v; B2[o] = b2v;
}

// M = (Wih @ W2) scaled per gate; dv = (Wih @ b2) scaled per gate.
__global__ __launch_bounds__(256) void make_M(const float* __restrict__ Wih, const float* __restrict__ W2,
    const float* __restrict__ b2, float* __restrict__ M, float* __restrict__ dv){
  int idx = blockIdx.x*256 + threadIdx.x;
  if (idx >= 12288) return;
  int o = idx >> 6, k = idx & 63;
  float sc = (o < 128) ? -LOG2E : 2.0f*LOG2E;
  float acc = 0.0f;
  for (int j = 0; j < 64; j++) acc += Wih[o*64+j]*W2[j*64+k];
  M[idx] = sc * acc;
  if (k == 0){
    float a2 = 0.0f;
    for (int j = 0; j < 64; j++) a2 += Wih[o*64+j]*b2[j];
    dv[o] = sc * a2;
  }
}

// ---------- per-node layer-1 + segment-sum on MFMA (pre-converted rows) ----------
__global__ __launch_bounds__(256, 2) void node_msg_kernel(
    const float* __restrict__ csr2, const int* __restrict__ off,
    const unsigned short* __restrict__ W1B1v, const unsigned short* __restrict__ W1B2v,
    const float* __restrict__ b1, float* __restrict__ hsum, int N)
{
  int t = threadIdx.x, lane = t & 63;
  int s_ = lane & 15, g_ = lane >> 4;
  const bf16x8* B1 = (const bf16x8*)W1B1v;
  const bf16x8* B2 = (const bf16x8*)W1B2v;
  bf16x8 w1b1[4], w1b2[4];
  #pragma unroll
  for (int c = 0; c < 4; c++){ w1b1[c] = B1[c*64+lane]; w1b2[c] = B2[c*64+lane]; }
  float b1f[4], rb1[4];
  #pragma unroll
  for (int c = 0; c < 4; c++){ b1f[c] = b1[c*16+s_]; rb1[c] = fmaxf(b1f[c], 0.f); }
  bool hi_ = (g_ < 2);
  int rofs_us = (g_ == 0) ? 0 : (g_ == 2) ? 8 : (g_ == 1) ? 16 : 20;
  int wid = (blockIdx.x*256 + t) >> 6;
  int nw = gridDim.x*4;
  for (int node = wid; node < N; node += nw){
    int s = off[node], e = off[node+1];
    float accR[4] = {0.f,0.f,0.f,0.f};
    int ntiles = (e - s + 15) >> 4;
    for (int tt = 0; tt < ntiles; tt++){
      int p = s + tt*16 + s_;
      bf16x8 af = {0,0,0,0,0,0,0,0};
      if (p < e){
        const unsigned short* row = (const unsigned short*)(csr2 + (size_t)p*16);
        if ((g_ & 1) == 0){
          af = *(const bf16x8*)(row + rofs_us);
        } else {
          short4 v = *(const short4*)(row + rofs_us);
          af[0]=v.x; af[1]=v.y; af[2]=v.z; af[3]=v.w;
        }
      }
      bf16x8 ah = hi_ ? af : (bf16x8){0,0,0,0,0,0,0,0};
      #pragma unroll
      for (int c = 0; c < 4; c++){
        f32x4 acc; acc[0]=b1f[c]; acc[1]=b1f[c]; acc[2]=b1f[c]; acc[3]=b1f[c];
        acc = __builtin_amdgcn_mfma_f32_16x16x32_bf16(af, w1b1[c], acc, 0,0,0);
        acc = __builtin_amdgcn_mfma_f32_16x16x32_bf16(ah, w1b2[c], acc, 0,0,0);
        accR[c] += fmaxf(acc[0],0.f)+fmaxf(acc[1],0.f)+fmaxf(acc[2],0.f)+fmaxf(acc[3],0.f);
      }
    }
    float npad = (float)(ntiles*16 - (e - s));
    #pragma unroll
    for (int c = 0; c < 4; c++){
      float v = accR[c] - npad*rb1[c];
      v += __shfl_xor(v, 16, 64);
      v += __shfl_xor(v, 32, 64);
      accR[c] = v;
    }
    float outv = (g_==0) ? accR[0] : ((g_==1) ? accR[1] : ((g_==2) ? accR[2] : accR[3]));
    hsum[(size_t)node*64 + lane] = outv;
  }
}

// ---------- fused (M@hsum + deg*dv + bih) + 6-step GRU on matrix cores ----------
__global__ __launch_bounds__(256, 2) void gru_mfma(
    float* hsumh,
    const unsigned short* __restrict__ MF, const unsigned short* __restrict__ WhhF,
    const float* __restrict__ bih, const float* __restrict__ bhh,
    const float* __restrict__ dv, const float* __restrict__ degf, int N)
{
  __shared__ __align__(16) unsigned short swhh[12288];   // 24 KB
  __shared__ unsigned short hbuf[4][1024];               // 8 KB
  __shared__ float sbi[192], sbh[192], sdv[192];         // 2.25 KB
  int t = threadIdx.x, lane = t & 63, w = t >> 6;
  int s_ = lane & 15, g_ = lane >> 4;
  unsigned short* hb = hbuf[w];

  {
    const u32x4* src = (const u32x4*)WhhF;
    u32x4* dst = (u32x4*)swhh;
    #pragma unroll
    for (int i = 0; i < 6; i++) dst[t + 256*i] = src[t + 256*i];
  }
  if (t < 192){ sbi[t] = bih[t]; sbh[t] = bhh[t]; sdv[t] = dv[t]; }
  __syncthreads();

  const bf16x8* WHH = (const bf16x8*)swhh;
  const bf16x8* MFV = (const bf16x8*)MF;

  float bhn[4];
  #pragma unroll
  for (int c = 0; c < 4; c++) bhn[c] = 2.0f*LOG2E * sbh[128 + c*16 + s_];

  int NT = (N + 15) >> 4;
  int wid = blockIdx.x*4 + w;
  int nw = gridDim.x*4;
  for (int tile = wid; tile < NT; tile += nw){
    // ---- A-fragments of hsum tile (16 nodes x 64 feats) ----
    int nodeA = tile*16 + s_; if (nodeA > N-1) nodeA = N-1;
    const float* ab = hsumh + (size_t)nodeA*64 + g_*8;
    float4 v0 = *(const float4*)(ab);
    float4 v1 = *(const float4*)(ab+4);
    float4 v2 = *(const float4*)(ab+32);
    float4 v3 = *(const float4*)(ab+36);
    bf16x8 a0, a1;
    a0[0]=(short)f2bf(v0.x); a0[1]=(short)f2bf(v0.y); a0[2]=(short)f2bf(v0.z); a0[3]=(short)f2bf(v0.w);
    a0[4]=(short)f2bf(v1.x); a0[5]=(short)f2bf(v1.y); a0[6]=(short)f2bf(v1.z); a0[7]=(short)f2bf(v1.w);
    a1[0]=(short)f2bf(v2.x); a1[1]=(short)f2bf(v2.y); a1[2]=(short)f2bf(v2.z); a1[3]=(short)f2bf(v2.w);
    a1[4]=(short)f2bf(v3.x); a1[5]=(short)f2bf(v3.y); a1[6]=(short)f2bf(v3.z); a1[7]=(short)f2bf(v3.w);

    // ---- gi (pre-scaled): gb = sc*(bih [+bhh]) + deg*dv' + M'@hsum, bf16-packed ----
    float4 dr = *(const float4*)(degf + tile*16 + 4*g_);
    float drr[4] = {dr.x, dr.y, dr.z, dr.w};
    bf16x8 gb[6];
    #pragma unroll
    for (int c = 0; c < 12; c++){
      float sc = (c < 8) ? -LOG2E : 2.0f*LOG2E;
      float bic = sc * (sbi[c*16 + s_] + ((c < 8) ? sbh[c*16 + s_] : 0.0f));
      float dvc = sdv[c*16 + s_];   // pre-scaled in make_M
      f32x4 acc;
      #pragma unroll
      for (int r = 0; r < 4; r++) acc[r] = bic + drr[r]*dvc;
      acc = __builtin_amdgcn_mfma_f32_16x16x32_bf16(a0, MFV[(c*2+0)*64 + lane], acc, 0, 0, 0);
      acc = __builtin_amdgcn_mfma_f32_16x16x32_bf16(a1, MFV[(c*2+1)*64 + lane], acc, 0, 0, 0);
      #pragma unroll
      for (int r = 0; r < 4; r++) gb[c>>1][(c&1)*4 + r] = (short)f2bf(acc[r]);
    }

    // ---- 6 GRU steps ----
    f32x4 hD[4];
    #pragma unroll
    for (int c = 0; c < 4; c++){ hD[c][0]=0.f; hD[c][1]=0.f; hD[c][2]=0.f; hD[c][3]=0.f; }
    bf16x8 h0 = {0,0,0,0,0,0,0,0};
    bf16x8 h1 = {0,0,0,0,0,0,0,0};
    for (int st = 0; st < 6; st++){
      // Opaque zero: defeats LICM hoisting of the 24 WHH ds_reads (R13 spill source).
      int zofs = 0;
      asm volatile("" : "+v"(zofs));
      #pragma unroll
      for (int c = 0; c < 4; c++){
        f32x4 aR, aZ, aN, giN;
        #pragma unroll
        for (int r = 0; r < 4; r++){
          aR[r]  = bf2f((unsigned short)gb[c>>1][(c&1)*4 + r]);
          aZ[r]  = bf2f((unsigned short)gb[(4+c)>>1][((4+c)&1)*4 + r]);
          giN[r] = bf2f((unsigned short)gb[(8+c)>>1][((8+c)&1)*4 + r]);
        }
        aN[0]=bhn[c]; aN[1]=bhn[c]; aN[2]=bhn[c]; aN[3]=bhn[c];
        aR = __builtin_amdgcn_mfma_f32_16x16x32_bf16(h0, WHH[(c*2)*64 + lane + zofs],       aR, 0,0,0);
        aR = __builtin_amdgcn_mfma_f32_16x16x32_bf16(h1, WHH[(c*2+1)*64 + lane + zofs],     aR, 0,0,0);
        aZ = __builtin_amdgcn_mfma_f32_16x16x32_bf16(h0, WHH[((4+c)*2)*64 + lane + zofs],   aZ, 0,0,0);
        aZ = __builtin_amdgcn_mfma_f32_16x16x32_bf16(h1, WHH[((4+c)*2+1)*64 + lane + zofs], aZ, 0,0,0);
        aN = __builtin_amdgcn_mfma_f32_16x16x32_bf16(h0, WHH[((8+c)*2)*64 + lane + zofs],   aN, 0,0,0);
        aN = __builtin_amdgcn_mfma_f32_16x16x32_bf16(h1, WHH[((8+c)*2+1)*64 + lane + zofs], aN, 0,0,0);
        #pragma unroll
        for (int r = 0; r < 4; r++){
          float rr = rcp_(1.0f + exp2_(aR[r]));
          float zz = rcp_(1.0f + exp2_(aZ[r]));
          float nn = 1.0f - 2.0f*rcp_(1.0f + exp2_(giN[r] + rr*aN[r]));
          hD[c][r] = nn + zz*(hD[c][r] - nn);
        }
      }
      if (st < 5){
        #pragma unroll
        for (int c = 0; c < 4; c++){
          #pragma unroll
          for (int r = 0; r < 4; r++){
            int nl = 4*g_ + r;
            int idx = (nl*64 + 16*c + s_) ^ ((nl & 7) << 3);
            hb[idx] = f2bf(hD[c][r]);
          }
        }
        int r0 = (s_*64 +      8*g_) ^ ((s_ & 7) << 3);
        int r1 = (s_*64 + 32 + 8*g_) ^ ((s_ & 7) << 3);
        h0 = *(const bf16x8*)(hb + r0);
        h1 = *(const bf16x8*)(hb + r1);
      }
    }
    // ---- store h ----
    #pragma unroll
    for (int c = 0; c < 4; c++){
      #pragma unroll
      for (int r = 0; r < 4; r++){
        int node = tile*16 + 4*g_ + r;
        if (node < N) hsumh[(size_t)node*64 + 16*c + s_] = hD[c][r];
      }
    }
  }
}

// ---------- graph ranges via binary search on sorted batch ----------
__global__ __launch_bounds__(256) void gstart_kernel(const int* __restrict__ batch, int* __restrict__ gstart, int N, int G){
  int g = blockIdx.x*256 + threadIdx.x;
  if (g > G) return;
  int lo = 0, hi = N;
  while (lo < hi){ int mid = (lo + hi) >> 1; if (batch[mid] < g) lo = mid + 1; else hi = mid; }
  gstart[g] = lo;
}

// wave per graph: mean over the graph's node range
__global__ __launch_bounds__(64) void pool_kernel(const float* __restrict__ hout, const int* __restrict__ gstart,
                                                  float* __restrict__ pooled, int G){
  int g = blockIdx.x; int lane = threadIdx.x;
  int s = gstart[g], e = gstart[g+1];
  float acc = 0.0f;
  for (int n = s; n < e; n++) acc += hout[(size_t)n*64 + lane];
  float c = fmaxf((float)(e - s), 1.0f);
  pooled[g*64 + lane] = acc / c;
}

// thread per graph: out = W2 relu(W1 pooled + b1) + b2
__global__ __launch_bounds__(256) void readout_kernel(
  const float* __restrict__ pooled,
  const float* __restrict__ W1, const float* __restrict__ b1,
  const float* __restrict__ W2, const float* __restrict__ b2,
  float* __restrict__ out, int G)
{
  __shared__ __align__(16) float sW1[64*64];
  __shared__ float sb1[64], sW2v[64];
  for (int i = threadIdx.x; i < 64*64; i += 256) sW1[i] = W1[i];
  if (threadIdx.x < 64){ sb1[threadIdx.x] = b1[threadIdx.x]; sW2v[threadIdx.x] = W2[threadIdx.x]; }
  __syncthreads();
  int g = blockIdx.x*256 + threadIdx.x;
  if (g >= G) return;
  float p[64];
  const float4* pp = (const float4*)(pooled + g*64);
  #pragma unroll
  for (int k4 = 0; k4 < 16; k4++){
    float4 v = pp[k4];
    p[4*k4] = v.x; p[4*k4+1] = v.y; p[4*k4+2] = v.z; p[4*k4+3] = v.w;
  }
  float acc = b2[0];
  for (int j = 0; j < 64; j++){
    const float4* wv4 = (const float4*)(sW1 + j*64);
    float tacc = sb1[j];
    #pragma unroll
    for (int k4 = 0; k4 < 16; k4++){
      float4 wv = wv4[k4];
      tacc += wv.x*p[4*k4] + wv.y*p[4*k4+1] + wv.z*p[4*k4+2] + wv.w*p[4*k4+3];
    }
    acc += sW2v[j]*fmaxf(tacc, 0.0f);
  }
  out[g] = acc;
}

extern "C" void kernel_launch(void* const* d_in, const int* in_sizes, int n_in,
                              void* d_out, int out_size, void* d_ws, size_t ws_size,
                              hipStream_t stream)
{
  const float* x    = (const float*)d_in[0];
  const int*   ei   = (const int*)  d_in[1];
  const float* ea   = (const float*)d_in[2];
  const int*   batch= (const int*)  d_in[3];
  const float* mW1  = (const float*)d_in[4];
  const float* mb1  = (const float*)d_in[5];
  const float* mW2  = (const float*)d_in[6];
  const float* mb2  = (const float*)d_in[7];
  const float* Wih  = (const float*)d_in[8];
  const float* Whh  = (const float*)d_in[9];
  const float* bih  = (const float*)d_in[10];
  const float* bhh  = (const float*)d_in[11];
  const float* rW1  = (const float*)d_in[12];
  const float* rb1  = (const float*)d_in[13];
  const float* rW2  = (const float*)d_in[14];
  const float* rb2  = (const float*)d_in[15];
  float* out = (float*)d_out;

  int N = in_sizes[0] / 9;
  int E = in_sizes[1] / 2;
  int G = out_size;

  float* fws    = (float*)d_ws;
  float* hsum   = fws;                          // 64N floats (in: hsum, out: h)
  int*   rank   = (int*)hsum;                   // E ints, aliases hsum
  float* csr2   = hsum + (size_t)64*N;          // 16E floats (64B rows, bf16 hi/lo layout)
  float* degf   = csr2 + (size_t)16*E;          // N+16
  float* M      = degf + (size_t)(N+16);        // 12288
  float* dv     = M + 12288;                    // 192
  float* pooled = dv + 192;                     // 64G
  unsigned short* MF   = (unsigned short*)(pooled + (size_t)64*G);  // 12288
  unsigned short* WhhF = MF + 12288;                                 // 12288
  unsigned short* W1B1 = WhhF + 12288;                               // 2048
  unsigned short* W1B2 = W1B1 + 2048;                                // 2048
  unsigned short* xp   = W1B2 + 2048;                                // 32N ushorts (64B rows)
  int*   iws    = (int*)(xp + (size_t)32*N);
  int*   cnt    = iws;                          // N
  int*   off    = cnt + N;                      // N+1
  int*   bsum   = off + N + 1;                  // up to 1024
  int*   gstart = bsum + 1024;                  // G+1

  int B1 = (N + CH - 1) / CH;

  hipMemsetAsync(cnt, 0, (size_t)N*sizeof(int), stream);
  hipMemsetAsync(degf + N, 0, 16*sizeof(float), stream);

  count_rank<<<(E+255)/256, 256, 0, stream>>>(ei, cnt, rank, E);
  scan_partial<<<B1, 256, 0, stream>>>(cnt, bsum, N);
  scan_bsum<<<1, 64, 0, stream>>>(bsum, B1);
  scan_final<<<B1, 256, 0, stream>>>(cnt, bsum, off, degf, N, E);
  xpack_kernel<<<(N+255)/256, 256, 0, stream>>>(x, xp, N);
  fill64<<<(E+255)/256, 256, 0, stream>>>(ei, xp, ea, off, rank, csr2, E);

  pack_w1<<<8, 256, 0, stream>>>(mW1, W1B1, W1B2);
  make_M<<<48, 256, 0, stream>>>(Wih, mW2, mb2, M, dv);
  pack_frag<<<48, 256, 0, stream>>>(M, MF, 1.0f, 1.0f);
  pack_frag<<<48, 256, 0, stream>>>(Whh, WhhF, -LOG2E, 2.0f*LOG2E);

  node_msg_kernel<<<1024, 256, 0, stream>>>(csr2, off, W1B1, W1B2, mb1, hsum, N);

  gru_mfma<<<1024, 256, 0, stream>>>(hsum, MF, WhhF, bih, bhh, dv, degf, N);

  gstart_kernel<<<(G+256)/256, 256, 0, stream>>>(batch, gstart, N, G);
  pool_kernel<<<G, 64, 0, stream>>>(hsum, gstart, pooled, G);
  readout_kernel<<<(G+255)/256, 256, 0, stream>>>(pooled, rW1, rb1, rW2, rb2, out, G);
}

// Round 21
// 321.370 us; speedup vs baseline: 1.4697x; 1.0359x over previous
//
#include <hip/hip_runtime.h>
#include <math.h>

#define CH 1024
#define LOG2E 1.4426950408889634f

typedef __attribute__((ext_vector_type(8))) short bf16x8;
typedef __attribute__((ext_vector_type(4))) float f32x4;
typedef __attribute__((ext_vector_type(4))) unsigned u32x4;

__device__ __forceinline__ float rcp_(float x){ return __builtin_amdgcn_rcpf(x); }
__device__ __forceinline__ float exp2_(float x){ return exp2f(x); }   // native v_exp_f32 (2^x)
__device__ __forceinline__ unsigned short f2bf(float f){
  union{float f;unsigned u;}v; v.f=f;
  unsigned r = v.u + 0x7fffu + ((v.u>>16)&1u);
  return (unsigned short)(r>>16);
}
__device__ __forceinline__ float bf2f(unsigned short u){
  union{unsigned u; float f;} v; v.u = ((unsigned)u) << 16; return v.f;
}

// ---------- CSR build ----------
__global__ __launch_bounds__(256) void count_rank(const int* __restrict__ ei, int* __restrict__ cnt,
                                                  int* __restrict__ rank, int E){
  int e = blockIdx.x*256 + threadIdx.x;
  if (e < E) rank[e] = atomicAdd(&cnt[ei[E + e]], 1);
}

__global__ __launch_bounds__(256) void scan_partial(const int* __restrict__ cnt, int* __restrict__ bsum, int N){
  __shared__ int s[256];
  int b = blockIdx.x, t = threadIdx.x;
  int base = b*CH;
  int sum = 0;
  for (int i = t; i < CH; i += 256){ int idx = base + i; sum += (idx < N) ? cnt[idx] : 0; }
  s[t] = sum; __syncthreads();
  for (int off = 128; off > 0; off >>= 1){ if (t < off) s[t] += s[t+off]; __syncthreads(); }
  if (t == 0) bsum[b] = s[0];
}

__global__ void scan_bsum(int* __restrict__ bsum, int B){
  if (threadIdx.x == 0 && blockIdx.x == 0){
    int acc = 0;
    for (int i = 0; i < B; i++){ int v = bsum[i]; bsum[i] = acc; acc += v; }
  }
}

__global__ __launch_bounds__(256) void scan_final(const int* __restrict__ cnt, const int* __restrict__ bsum,
                                                  int* __restrict__ off, float* __restrict__ degf, int N, int E){
  __shared__ int s[256];
  __shared__ int sx[256];
  int b = blockIdx.x, t = threadIdx.x;
  int i0 = b*CH + t*4;
  int v0 = (i0   < N) ? cnt[i0]   : 0;
  int v1 = (i0+1 < N) ? cnt[i0+1] : 0;
  int v2 = (i0+2 < N) ? cnt[i0+2] : 0;
  int v3 = (i0+3 < N) ? cnt[i0+3] : 0;
  s[t] = v0+v1+v2+v3; __syncthreads();
  if (t == 0){ int acc = bsum[b]; for (int i = 0; i < 256; i++){ sx[i] = acc; acc += s[i]; } }
  __syncthreads();
  int acc = sx[t];
  if (i0   < N){ off[i0]   = acc; degf[i0]   = (float)v0; } acc += v0;
  if (i0+1 < N){ off[i0+1] = acc; degf[i0+1] = (float)v1; } acc += v1;
  if (i0+2 < N){ off[i0+2] = acc; degf[i0+2] = (float)v2; } acc += v2;
  if (i0+3 < N){ off[i0+3] = acc; degf[i0+3] = (float)v3; }
  if (b == 0 && t == 0) off[N] = E;
}

// pre-convert x rows to bf16 hi/lo, 64B-aligned: [hi0..7|16B][lo0..7|16B][hi8,lo8|4B][pad]
__global__ __launch_bounds__(256) void xpack_kernel(const float* __restrict__ x, unsigned short* __restrict__ xp, int N){
  int n = blockIdx.x*256 + threadIdx.x;
  if (n >= N) return;
  const float* xr = x + (size_t)n*9;
  union { unsigned short us[32]; u32x4 q[4]; } row;
  #pragma unroll
  for (int i = 0; i < 9; i++){
    unsigned short hi = f2bf(xr[i]);
    unsigned short lo = f2bf(xr[i] - bf2f(hi));
    if (i < 8){ row.us[i] = hi; row.us[8+i] = lo; }
    else { row.us[16] = hi; row.us[17] = lo; }
  }
  #pragma unroll
  for (int i = 18; i < 32; i++) row.us[i] = 0;
  u32x4* dstp = (u32x4*)(xp + (size_t)n*32);
  dstp[0] = row.q[0]; dstp[1] = row.q[1]; dstp[2] = row.q[2]; dstp[3] = row.q[3];
}

// 16B record per edge at CSR position: {src, eah0|eah1, eah2|eal0, eal1|eal2}.
// Scatter payload shrinks 64B->16B (102->25.6 MB); node_msg re-derives x from xp.
__global__ __launch_bounds__(256) void fill_rec(const int* __restrict__ ei, const float* __restrict__ ea,
                                                const int* __restrict__ off, const int* __restrict__ rank,
                                                u32x4* __restrict__ rec, int E){
  int e = blockIdx.x*256 + threadIdx.x;
  if (e >= E) return;
  int dst = ei[E + e];
  int src = ei[e];
  int p = off[dst] + rank[e];
  const float* er = ea + (size_t)e*3;
  float e0 = er[0], e1 = er[1], e2 = er[2];
  unsigned short eh0 = f2bf(e0), eh1 = f2bf(e1), eh2 = f2bf(e2);
  unsigned short el0 = f2bf(e0 - bf2f(eh0));
  unsigned short el1 = f2bf(e1 - bf2f(eh1));
  unsigned short el2 = f2bf(e2 - bf2f(eh2));
  u32x4 r;
  r.x = (unsigned)src;
  r.y = (unsigned)eh0 | ((unsigned)eh1 << 16);
  r.z = (unsigned)eh2 | ((unsigned)el0 << 16);
  r.w = (unsigned)el1 | ((unsigned)el2 << 16);
  rec[p] = r;
}

// pack a [192][64] gate matrix into bf16 B-fragments, with per-gate scaling
__global__ __launch_bounds__(256) void pack_frag(const float* __restrict__ W, unsigned short* __restrict__ P,
                                                 float sRZ, float sN){
  int o = blockIdx.x*256 + threadIdx.x;
  if (o >= 12288) return;
  int j = o & 7, l = (o>>3)&63, kh = (o>>9)&1, c = o>>10;
  float sc = (c < 8) ? sRZ : sN;
  P[o] = f2bf(sc * W[(c*16 + (l&15))*64 + kh*32 + 8*(l>>4) + j]);
}

// W1 [64][12] -> two B-fragment sets over K=32 (hi/lo split)
__global__ __launch_bounds__(256) void pack_w1(const float* __restrict__ W1,
    unsigned short* __restrict__ B1, unsigned short* __restrict__ B2){
  int o = blockIdx.x*256 + threadIdx.x;
  if (o >= 2048) return;
  int j = o & 7, l = (o>>3) & 63, c = o >> 9;
  int n = c*16 + (l & 15);
  int kk = 8*(l>>4) + j;
  unsigned short b1v = 0, b2v = 0;
  if (kk < 12){
    float w = W1[n*12 + kk];
    unsigned short hi = f2bf(w);
    b1v = hi;
    b2v = f2bf(w - bf2f(hi));
  } else if (kk >= 16 && kk < 28){
    b1v = f2bf(W1[n*12 + (kk-16)]);
  }
  B1[o] = b1v; B2[o] = b2v;
}

// M = (Wih @ W2) scaled per gate; dv = (Wih @ b2) scaled per gate.
__global__ __launch_bounds__(256) void make_M(const float* __restrict__ Wih, const float* __restrict__ W2,
    const float* __restrict__ b2, float* __restrict__ M, float* __restrict__ dv){
  int idx = blockIdx.x*256 + threadIdx.x;
  if (idx >= 12288) return;
  int o = idx >> 6, k = idx & 63;
  float sc = (o < 128) ? -LOG2E : 2.0f*LOG2E;
  float acc = 0.0f;
  for (int j = 0; j < 64; j++) acc += Wih[o*64+j]*W2[j*64+k];
  M[idx] = sc * acc;
  if (k == 0){
    float a2 = 0.0f;
    for (int j = 0; j < 64; j++) a2 += Wih[o*64+j]*b2[j];
    dv[o] = sc * a2;
  }
}

// ---------- per-node layer-1 + segment-sum on MFMA (record + xp assembly) ----------
// A-frag: g_=0: xp hi0..7 (k0..7); g_=1: {hi8, eah0..2} (k8..11); g_=2: xp lo0..7
// (k16..23); g_=3: {lo8, eal0..2} (k24..27). Same K layout as before.
__global__ __launch_bounds__(256, 2) void node_msg_kernel(
    const u32x4* __restrict__ rec, const unsigned short* __restrict__ xp, const int* __restrict__ off,
    const unsigned short* __restrict__ W1B1v, const unsigned short* __restrict__ W1B2v,
    const float* __restrict__ b1, float* __restrict__ hsum, int N)
{
  int t = threadIdx.x, lane = t & 63;
  int s_ = lane & 15, g_ = lane >> 4;
  const bf16x8* B1 = (const bf16x8*)W1B1v;
  const bf16x8* B2 = (const bf16x8*)W1B2v;
  bf16x8 w1b1[4], w1b2[4];
  #pragma unroll
  for (int c = 0; c < 4; c++){ w1b1[c] = B1[c*64+lane]; w1b2[c] = B2[c*64+lane]; }
  float b1f[4], rb1[4];
  #pragma unroll
  for (int c = 0; c < 4; c++){ b1f[c] = b1[c*16+s_]; rb1[c] = fmaxf(b1f[c], 0.f); }
  bool hi_ = (g_ < 2);
  int wid = (blockIdx.x*256 + t) >> 6;
  int nw = gridDim.x*4;
  for (int node = wid; node < N; node += nw){
    int s = off[node], e = off[node+1];
    float accR[4] = {0.f,0.f,0.f,0.f};
    int ntiles = (e - s + 15) >> 4;
    for (int tt = 0; tt < ntiles; tt++){
      int p = s + tt*16 + s_;
      bf16x8 af = {0,0,0,0,0,0,0,0};
      if (p < e){
        u32x4 r = rec[p];
        int src = (int)r.x;
        const unsigned short* xr = xp + (size_t)src*32;
        if ((g_ & 1) == 0){
          af = *(const bf16x8*)(xr + ((g_ == 0) ? 0 : 8));
        } else {
          unsigned hl8 = *(const unsigned*)(xr + 16);
          if (g_ == 1){
            af[0] = (short)(hl8 & 0xFFFFu);
            af[1] = (short)(r.y & 0xFFFFu);
            af[2] = (short)(r.y >> 16);
            af[3] = (short)(r.z & 0xFFFFu);
          } else {
            af[0] = (short)(hl8 >> 16);
            af[1] = (short)(r.z >> 16);
            af[2] = (short)(r.w & 0xFFFFu);
            af[3] = (short)(r.w >> 16);
          }
        }
      }
      bf16x8 ah = hi_ ? af : (bf16x8){0,0,0,0,0,0,0,0};
      #pragma unroll
      for (int c = 0; c < 4; c++){
        f32x4 acc; acc[0]=b1f[c]; acc[1]=b1f[c]; acc[2]=b1f[c]; acc[3]=b1f[c];
        acc = __builtin_amdgcn_mfma_f32_16x16x32_bf16(af, w1b1[c], acc, 0,0,0);
        acc = __builtin_amdgcn_mfma_f32_16x16x32_bf16(ah, w1b2[c], acc, 0,0,0);
        accR[c] += fmaxf(acc[0],0.f)+fmaxf(acc[1],0.f)+fmaxf(acc[2],0.f)+fmaxf(acc[3],0.f);
      }
    }
    float npad = (float)(ntiles*16 - (e - s));
    #pragma unroll
    for (int c = 0; c < 4; c++){
      float v = accR[c] - npad*rb1[c];
      v += __shfl_xor(v, 16, 64);
      v += __shfl_xor(v, 32, 64);
      accR[c] = v;
    }
    float outv = (g_==0) ? accR[0] : ((g_==1) ? accR[1] : ((g_==2) ? accR[2] : accR[3]));
    hsum[(size_t)node*64 + lane] = outv;
  }
}

// ---------- fused (M@hsum + deg*dv + bih) + 6-step GRU on matrix cores ----------
__global__ __launch_bounds__(256, 2) void gru_mfma(
    float* hsumh,
    const unsigned short* __restrict__ MF, const unsigned short* __restrict__ WhhF,
    const float* __restrict__ bih, const float* __restrict__ bhh,
    const float* __restrict__ dv, const float* __restrict__ degf, int N)
{
  __shared__ __align__(16) unsigned short swhh[12288];   // 24 KB
  __shared__ unsigned short hbuf[4][1024];               // 8 KB
  __shared__ float sbi[192], sbh[192], sdv[192];         // 2.25 KB
  int t = threadIdx.x, lane = t & 63, w = t >> 6;
  int s_ = lane & 15, g_ = lane >> 4;
  unsigned short* hb = hbuf[w];

  {
    const u32x4* src = (const u32x4*)WhhF;
    u32x4* dst = (u32x4*)swhh;
    #pragma unroll
    for (int i = 0; i < 6; i++) dst[t + 256*i] = src[t + 256*i];
  }
  if (t < 192){ sbi[t] = bih[t]; sbh[t] = bhh[t]; sdv[t] = dv[t]; }
  __syncthreads();

  const bf16x8* WHH = (const bf16x8*)swhh;
  const bf16x8* MFV = (const bf16x8*)MF;

  float bhn[4];
  #pragma unroll
  for (int c = 0; c < 4; c++) bhn[c] = 2.0f*LOG2E * sbh[128 + c*16 + s_];

  int NT = (N + 15) >> 4;
  int wid = blockIdx.x*4 + w;
  int nw = gridDim.x*4;
  for (int tile = wid; tile < NT; tile += nw){
    // ---- A-fragments of hsum tile (16 nodes x 64 feats) ----
    int nodeA = tile*16 + s_; if (nodeA > N-1) nodeA = N-1;
    const float* ab = hsumh + (size_t)nodeA*64 + g_*8;
    float4 v0 = *(const float4*)(ab);
    float4 v1 = *(const float4*)(ab+4);
    float4 v2 = *(const float4*)(ab+32);
    float4 v3 = *(const float4*)(ab+36);
    bf16x8 a0, a1;
    a0[0]=(short)f2bf(v0.x); a0[1]=(short)f2bf(v0.y); a0[2]=(short)f2bf(v0.z); a0[3]=(short)f2bf(v0.w);
    a0[4]=(short)f2bf(v1.x); a0[5]=(short)f2bf(v1.y); a0[6]=(short)f2bf(v1.z); a0[7]=(short)f2bf(v1.w);
    a1[0]=(short)f2bf(v2.x); a1[1]=(short)f2bf(v2.y); a1[2]=(short)f2bf(v2.z); a1[3]=(short)f2bf(v2.w);
    a1[4]=(short)f2bf(v3.x); a1[5]=(short)f2bf(v3.y); a1[6]=(short)f2bf(v3.z); a1[7]=(short)f2bf(v3.w);

    // ---- gi (pre-scaled): gb = sc*(bih [+bhh]) + deg*dv' + M'@hsum, bf16-packed ----
    float4 dr = *(const float4*)(degf + tile*16 + 4*g_);
    float drr[4] = {dr.x, dr.y, dr.z, dr.w};
    bf16x8 gb[6];
    #pragma unroll
    for (int c = 0; c < 12; c++){
      float sc = (c < 8) ? -LOG2E : 2.0f*LOG2E;
      float bic = sc * (sbi[c*16 + s_] + ((c < 8) ? sbh[c*16 + s_] : 0.0f));
      float dvc = sdv[c*16 + s_];   // pre-scaled in make_M
      f32x4 acc;
      #pragma unroll
      for (int r = 0; r < 4; r++) acc[r] = bic + drr[r]*dvc;
      acc = __builtin_amdgcn_mfma_f32_16x16x32_bf16(a0, MFV[(c*2+0)*64 + lane], acc, 0, 0, 0);
      acc = __builtin_amdgcn_mfma_f32_16x16x32_bf16(a1, MFV[(c*2+1)*64 + lane], acc, 0, 0, 0);
      #pragma unroll
      for (int r = 0; r < 4; r++) gb[c>>1][(c&1)*4 + r] = (short)f2bf(acc[r]);
    }

    // ---- 6 GRU steps ----
    f32x4 hD[4];
    #pragma unroll
    for (int c = 0; c < 4; c++){ hD[c][0]=0.f; hD[c][1]=0.f; hD[c][2]=0.f; hD[c][3]=0.f; }
    bf16x8 h0 = {0,0,0,0,0,0,0,0};
    bf16x8 h1 = {0,0,0,0,0,0,0,0};
    for (int st = 0; st < 6; st++){
      // Opaque zero: defeats LICM hoisting of the 24 WHH ds_reads (R13 spill source).
      int zofs = 0;
      asm volatile("" : "+v"(zofs));
      #pragma unroll
      for (int c = 0; c < 4; c++){
        f32x4 aR, aZ, aN, giN;
        #pragma unroll
        for (int r = 0; r < 4; r++){
          aR[r]  = bf2f((unsigned short)gb[c>>1][(c&1)*4 + r]);
          aZ[r]  = bf2f((unsigned short)gb[(4+c)>>1][((4+c)&1)*4 + r]);
          giN[r] = bf2f((unsigned short)gb[(8+c)>>1][((8+c)&1)*4 + r]);
        }
        aN[0]=bhn[c]; aN[1]=bhn[c]; aN[2]=bhn[c]; aN[3]=bhn[c];
        aR = __builtin_amdgcn_mfma_f32_16x16x32_bf16(h0, WHH[(c*2)*64 + lane + zofs],       aR, 0,0,0);
        aR = __builtin_amdgcn_mfma_f32_16x16x32_bf16(h1, WHH[(c*2+1)*64 + lane + zofs],     aR, 0,0,0);
        aZ = __builtin_amdgcn_mfma_f32_16x16x32_bf16(h0, WHH[((4+c)*2)*64 + lane + zofs],   aZ, 0,0,0);
        aZ = __builtin_amdgcn_mfma_f32_16x16x32_bf16(h1, WHH[((4+c)*2+1)*64 + lane + zofs], aZ, 0,0,0);
        aN = __builtin_amdgcn_mfma_f32_16x16x32_bf16(h0, WHH[((8+c)*2)*64 + lane + zofs],   aN, 0,0,0);
        aN = __builtin_amdgcn_mfma_f32_16x16x32_bf16(h1, WHH[((8+c)*2+1)*64 + lane + zofs], aN, 0,0,0);
        #pragma unroll
        for (int r = 0; r < 4; r++){
          float rr = rcp_(1.0f + exp2_(aR[r]));
          float zz = rcp_(1.0f + exp2_(aZ[r]));
          float nn = 1.0f - 2.0f*rcp_(1.0f + exp2_(giN[r] + rr*aN[r]));
          hD[c][r] = nn + zz*(hD[c][r] - nn);
        }
      }
      if (st < 5){
        #pragma unroll
        for (int c = 0; c < 4; c++){
          #pragma unroll
          for (int r = 0; r < 4; r++){
            int nl = 4*g_ + r;
            int idx = (nl*64 + 16*c + s_) ^ ((nl & 7) << 3);
            hb[idx] = f2bf(hD[c][r]);
          }
        }
        int r0 = (s_*64 +      8*g_) ^ ((s_ & 7) << 3);
        int r1 = (s_*64 + 32 + 8*g_) ^ ((s_ & 7) << 3);
        h0 = *(const bf16x8*)(hb + r0);
        h1 = *(const bf16x8*)(hb + r1);
      }
    }
    // ---- store h ----
    #pragma unroll
    for (int c = 0; c < 4; c++){
      #pragma unroll
      for (int r = 0; r < 4; r++){
        int node = tile*16 + 4*g_ + r;
        if (node < N) hsumh[(size_t)node*64 + 16*c + s_] = hD[c][r];
      }
    }
  }
}

// ---------- graph ranges via binary search on sorted batch ----------
__global__ __launch_bounds__(256) void gstart_kernel(const int* __restrict__ batch, int* __restrict__ gstart, int N, int G){
  int g = blockIdx.x*256 + threadIdx.x;
  if (g > G) return;
  int lo = 0, hi = N;
  while (lo < hi){ int mid = (lo + hi) >> 1; if (batch[mid] < g) lo = mid + 1; else hi = mid; }
  gstart[g] = lo;
}

// wave per graph: mean over the graph's node range
__global__ __launch_bounds__(64) void pool_kernel(const float* __restrict__ hout, const int* __restrict__ gstart,
                                                  float* __restrict__ pooled, int G){
  int g = blockIdx.x; int lane = threadIdx.x;
  int s = gstart[g], e = gstart[g+1];
  float acc = 0.0f;
  for (int n = s; n < e; n++) acc += hout[(size_t)n*64 + lane];
  float c = fmaxf((float)(e - s), 1.0f);
  pooled[g*64 + lane] = acc / c;
}

// thread per graph: out = W2 relu(W1 pooled + b1) + b2
__global__ __launch_bounds__(256) void readout_kernel(
  const float* __restrict__ pooled,
  const float* __restrict__ W1, const float* __restrict__ b1,
  const float* __restrict__ W2, const float* __restrict__ b2,
  float* __restrict__ out, int G)
{
  __shared__ __align__(16) float sW1[64*64];
  __shared__ float sb1[64], sW2v[64];
  for (int i = threadIdx.x; i < 64*64; i += 256) sW1[i] = W1[i];
  if (threadIdx.x < 64){ sb1[threadIdx.x] = b1[threadIdx.x]; sW2v[threadIdx.x] = W2[threadIdx.x]; }
  __syncthreads();
  int g = blockIdx.x*256 + threadIdx.x;
  if (g >= G) return;
  float p[64];
  const float4* pp = (const float4*)(pooled + g*64);
  #pragma unroll
  for (int k4 = 0; k4 < 16; k4++){
    float4 v = pp[k4];
    p[4*k4] = v.x; p[4*k4+1] = v.y; p[4*k4+2] = v.z; p[4*k4+3] = v.w;
  }
  float acc = b2[0];
  for (int j = 0; j < 64; j++){
    const float4* wv4 = (const float4*)(sW1 + j*64);
    float tacc = sb1[j];
    #pragma unroll
    for (int k4 = 0; k4 < 16; k4++){
      float4 wv = wv4[k4];
      tacc += wv.x*p[4*k4] + wv.y*p[4*k4+1] + wv.z*p[4*k4+2] + wv.w*p[4*k4+3];
    }
    acc += sW2v[j]*fmaxf(tacc, 0.0f);
  }
  out[g] = acc;
}

extern "C" void kernel_launch(void* const* d_in, const int* in_sizes, int n_in,
                              void* d_out, int out_size, void* d_ws, size_t ws_size,
                              hipStream_t stream)
{
  const float* x    = (const float*)d_in[0];
  const int*   ei   = (const int*)  d_in[1];
  const float* ea   = (const float*)d_in[2];
  const int*   batch= (const int*)  d_in[3];
  const float* mW1  = (const float*)d_in[4];
  const float* mb1  = (const float*)d_in[5];
  const float* mW2  = (const float*)d_in[6];
  const float* mb2  = (const float*)d_in[7];
  const float* Wih  = (const float*)d_in[8];
  const float* Whh  = (const float*)d_in[9];
  const float* bih  = (const float*)d_in[10];
  const float* bhh  = (const float*)d_in[11];
  const float* rW1  = (const float*)d_in[12];
  const float* rb1  = (const float*)d_in[13];
  const float* rW2  = (const float*)d_in[14];
  const float* rb2  = (const float*)d_in[15];
  float* out = (float*)d_out;

  int N = in_sizes[0] / 9;
  int E = in_sizes[1] / 2;
  int G = out_size;

  float* fws    = (float*)d_ws;
  float* hsum   = fws;                          // 64N floats (in: hsum, out: h)
  int*   rank   = (int*)hsum;                   // E ints, aliases hsum
  float* recf   = hsum + (size_t)64*N;          // 4E floats (16B records)
  float* degf   = recf + (size_t)4*E;           // N+16
  float* M      = degf + (size_t)(N+16);        // 12288
  float* dv     = M + 12288;                    // 192
  float* pooled = dv + 192;                     // 64G
  unsigned short* MF   = (unsigned short*)(pooled + (size_t)64*G);  // 12288
  unsigned short* WhhF = MF + 12288;                                 // 12288
  unsigned short* W1B1 = WhhF + 12288;                               // 2048
  unsigned short* W1B2 = W1B1 + 2048;                                // 2048
  unsigned short* xp   = W1B2 + 2048;                                // 32N ushorts (64B rows)
  int*   iws    = (int*)(xp + (size_t)32*N);
  int*   cnt    = iws;                          // N
  int*   off    = cnt + N;                      // N+1
  int*   bsum   = off + N + 1;                  // up to 1024
  int*   gstart = bsum + 1024;                  // G+1
  u32x4* rec    = (u32x4*)recf;

  int B1 = (N + CH - 1) / CH;

  hipMemsetAsync(cnt, 0, (size_t)N*sizeof(int), stream);
  hipMemsetAsync(degf + N, 0, 16*sizeof(float), stream);

  count_rank<<<(E+255)/256, 256, 0, stream>>>(ei, cnt, rank, E);
  scan_partial<<<B1, 256, 0, stream>>>(cnt, bsum, N);
  scan_bsum<<<1, 64, 0, stream>>>(bsum, B1);
  scan_final<<<B1, 256, 0, stream>>>(cnt, bsum, off, degf, N, E);
  xpack_kernel<<<(N+255)/256, 256, 0, stream>>>(x, xp, N);
  fill_rec<<<(E+255)/256, 256, 0, stream>>>(ei, ea, off, rank, rec, E);

  pack_w1<<<8, 256, 0, stream>>>(mW1, W1B1, W1B2);
  make_M<<<48, 256, 0, stream>>>(Wih, mW2, mb2, M, dv);
  pack_frag<<<48, 256, 0, stream>>>(M, MF, 1.0f, 1.0f);
  pack_frag<<<48, 256, 0, stream>>>(Whh, WhhF, -LOG2E, 2.0f*LOG2E);

  node_msg_kernel<<<1024, 256, 0, stream>>>(rec, xp, off, W1B1, W1B2, mb1, hsum, N);

  gru_mfma<<<1024, 256, 0, stream>>>(hsum, MF, WhhF, bih, bhh, dv, degf, N);

  gstart_kernel<<<(G+256)/256, 256, 0, stream>>>(batch, gstart, N, G);
  pool_kernel<<<G, 64, 0, stream>>>(hsum, gstart, pooled, G);
  readout_kernel<<<(G+255)/256, 256, 0, stream>>>(pooled, rW1, rb1, rW2, rb2, out, G);
}